// Round 9
// baseline (131.090 us; speedup 1.0000x reference)
//
#include <hip/hip_runtime.h>
#include <stdint.h>
#include <math.h>

#define Hh 128
#define Ww 128
#define Vn 16
#define An 8
#define Pn 64
#define Cn 3
#define HWc (Hh*Ww)
#define MAXT 50
#define PBLK 64   // k_prep blocks (256 threads each)

// DIRS = [(1,0),(0,1),(-1,0),(0,-1),(1,1),(-1,1),(1,-1),(-1,-1)]  (dr, dc)
__constant__ int c_DR[8] = {1, 0, -1, 0, 1, -1, 1, -1};
__constant__ int c_DC[8] = {0, 1, 0, -1, 1, 1, -1, -1};

__device__ __forceinline__ void softmaxN(const float* __restrict__ w, float* __restrict__ o, int n) {
  float m = -INFINITY;
  for (int i = 0; i < n; ++i) m = fmaxf(m, w[i]);
  float s = 0.f;
  for (int i = 0; i < n; ++i) { float e = expf(w[i] - m); o[i] = e; s += e; }
  float inv = 1.f / s;
  for (int i = 0; i < n; ++i) o[i] *= inv;
}

// ---- prep: conv3x3(zero-pad)+argmax; per-block first-occurrence reduced in
//      LDS (global atomicMax to one line serialized at ~4.7ns/op = 77us, R7),
//      then plain stores to bf[block][16]. enc = HWc - cell, 0 = absent.
__global__ __launch_bounds__(256) void k_prep(const float* __restrict__ obs,
                                              const float* __restrict__ cw,
                                              const float* __restrict__ cb,
                                              uint8_t* __restrict__ grid8,
                                              int* __restrict__ bf) {
  __shared__ float sw[Vn * Cn * 9];
  __shared__ float sb[Vn];
  __shared__ int lf[Vn];
  int t = threadIdx.x;
  for (int i = t; i < Vn * Cn * 9; i += 256) sw[i] = cw[i];
  if (t < Vn) { sb[t] = cb[t]; lf[t] = 0; }
  __syncthreads();

  int cell = blockIdx.x * 256 + t;
  int r = cell >> 7, c = cell & 127;
  // hoist the 27 obs taps (zero-padding == SAME conv semantics)
  float o[27];
#pragma unroll
  for (int ch = 0; ch < Cn; ++ch)
#pragma unroll
    for (int ky = 0; ky < 3; ++ky)
#pragma unroll
      for (int kx = 0; kx < 3; ++kx) {
        int rr = r + ky - 1, cc = c + kx - 1;
        o[ch * 9 + ky * 3 + kx] =
            ((unsigned)rr < (unsigned)Hh && (unsigned)cc < (unsigned)Ww)
                ? obs[(ch * Hh + rr) * Ww + cc] : 0.f;
      }
  float best = -INFINITY; int bi = 0;
#pragma unroll
  for (int v = 0; v < Vn; ++v) {
    float acc = sb[v];
#pragma unroll
    for (int i = 0; i < 27; ++i) acc += o[i] * sw[v * 27 + i];
    if (acc > best) { best = acc; bi = v; }  // first max on tie
  }
  grid8[cell] = (uint8_t)bi;
  atomicMax(&lf[bi], HWc - cell);            // LDS atomic — fast
  __syncthreads();
  if (t < Vn) bf[blockIdx.x * Vn + t] = lf[t];  // plain store
}

// ---- everything else in ONE block (1024 thr = 16 waves), all state in LDS:
// bf-reduce -> firsts; pi tables; cond table via wave-parallel ray ballots
// (lane t = ray step t+1, 16 ballots -> F[v], cond = F[sp]<inf && F[sp]<=F[sn]);
// expected counts  counts[a] = sum_p 16384*pi_act[p][a]*r_p,
//   r_p = q_p*pi_not[p][0]+(1-q_p)*pi_not[p][1],
//   q_p = sum_{o,d,pos,neg} pi_obj pi_dir pi_pos pi_neg * bit;
// then softmax(counts) -> out. Math identical to R7/R8-verified kernels.
__global__ __launch_bounds__(1024) void k_final(const uint8_t* __restrict__ grid8g,
                                                const int* __restrict__ bf,
                                                const float* __restrict__ w_obj,
                                                const float* __restrict__ w_pos,
                                                const float* __restrict__ w_neg,
                                                const float* __restrict__ w_act,
                                                const float* __restrict__ w_dir,
                                                const float* __restrict__ w_not,
                                                float* __restrict__ out) {
  __shared__ uint8_t g8[HWc];          // 16 KB
  __shared__ float sPi[4224];          // 17 KB
  __shared__ uint32_t sTab[1024];      // 4 KB
  __shared__ int lf16[Vn];
  __shared__ int sEx[Vn], sFr[Vn], sFc[Vn];
  __shared__ uint8_t Fv[16][16];
  __shared__ uint8_t nib[16][64];
  __shared__ float sCnt[An];

  int t = threadIdx.x;
  int wave = t >> 6, lane = t & 63;

  if (t < Vn) lf16[t] = 0;
  if (t < An) sCnt[t] = 0.f;
  __syncthreads();

  // stage grid: 16384 B / 16 B = 1024 -> one uint4 per thread
  ((uint4*)g8)[t] = ((const uint4*)grid8g)[t];
  // reduce per-block firsts (64 blocks x 16 values = 1024 ints)
  atomicMax(&lf16[t & 15], bf[t]);
  // pi tables: 384 softmax tasks
  if (t < 384) {
    int grp = t >> 6, p = t & 63;
    if      (grp == 0) softmaxN(w_obj + p * 16, sPi + p * 16,        16);
    else if (grp == 1) softmaxN(w_pos + p * 16, sPi + 1024 + p * 16, 16);
    else if (grp == 2) softmaxN(w_neg + p * 16, sPi + 2048 + p * 16, 16);
    else if (grp == 3) softmaxN(w_act + p * 8,  sPi + 3072 + p * 8,  8);
    else if (grp == 4) softmaxN(w_dir + p * 8,  sPi + 3584 + p * 8,  8);
    else               softmaxN(w_not + p * 2,  sPi + 4096 + p * 2,  2);
  }
  __syncthreads();
  if (t < Vn) {
    int m = lf16[t];
    int ex = (m >= 1);
    sEx[t] = ex;
    int cell = ex ? (HWc - m) : 0;
    sFr[t] = cell >> 7;
    sFc[t] = cell & 127;
  }
  __syncthreads();

  // cond table: 128 (so,sd) combos, 8 per wave
  for (int j = 0; j < 8; ++j) {
    int W = wave * 8 + j;          // 0..127
    int so = W >> 3, sd = W & 7;
    int step = lane + 1;
    int val = 255;                 // matches no object value
    if (step <= MAXT && sEx[so]) {
      int r = sFr[so] + step * c_DR[sd];
      int c = sFc[so] + step * c_DC[sd];
      if ((unsigned)r < (unsigned)Hh && (unsigned)c < (unsigned)Ww)
        val = g8[(r << 7) + c];
    }
#pragma unroll
    for (int v = 0; v < Vn; ++v) {
      unsigned long long m = __ballot(val == v);
      if (lane == v) Fv[wave][v] = m ? (uint8_t)__builtin_ctzll(m) : (uint8_t)64;
    }
    __syncthreads();
    uint32_t nb = 0;
#pragma unroll
    for (int k2 = 0; k2 < 4; ++k2) {
      int qq = lane * 4 + k2;      // (sp,sn) pair index 0..255
      int fp = Fv[wave][(qq >> 4) & 15];
      int fn = Fv[wave][qq & 15];
      nb |= ((fp < 64 && fp <= fn) ? 1u : 0u) << k2;
    }
    nib[wave][lane] = (uint8_t)nb;
    __syncthreads();
    if (lane < 8) {
      uint32_t w = 0;
#pragma unroll
      for (int jj = 0; jj < 8; ++jj) w |= (uint32_t)nib[wave][lane * 8 + jj] << (4 * jj);
      sTab[W * 8 + lane] = w;
    }
  }
  __syncthreads();

  // expected counts: 4 programs per wave
#pragma unroll
  for (int k = 0; k < 4; ++k) {
    int p = wave * 4 + k;          // 0..63
    const float* pObj = sPi + p * 16;
    const float* pPos = sPi + 1024 + p * 16;
    const float* pNeg = sPi + 2048 + p * 16;
    const float* pAct = sPi + 3072 + p * 8;
    const float* pDir = sPi + 3584 + p * 8;
    const float* pNot = sPi + 4096 + p * 2;

    float Ppos[16], Pneg[16];
#pragma unroll
    for (int i = 0; i < 16; ++i) { Ppos[i] = pPos[i]; Pneg[i] = pNeg[i]; }

    float acc = 0.f;
#pragma unroll
    for (int rep = 0; rep < 2; ++rep) {
      int od = lane + rep * 64;    // 0..127
      int o = od >> 3, d = od & 7;
      float w8 = pObj[o] * pDir[d];
      int base = od * 8;
      float inner = 0.f;
#pragma unroll
      for (int pos = 0; pos < 16; ++pos) {
        uint32_t bits = (sTab[base + (pos >> 1)] >> ((pos & 1) * 16)) & 0xFFFFu;
        float sneg = 0.f;
#pragma unroll
        for (int n = 0; n < 16; ++n)
          sneg += ((bits >> n) & 1u) ? Pneg[n] : 0.f;
        inner += Ppos[pos] * sneg;
      }
      acc += w8 * inner;
    }
#pragma unroll
    for (int off = 32; off >= 1; off >>= 1)
      acc += __shfl_down(acc, off, 64);

    if (lane == 0) {
      float q = acc;
      float r = q * pNot[0] + (1.f - q) * pNot[1];
      float scale = 16384.f * r;
#pragma unroll
      for (int a = 0; a < 8; ++a)
        atomicAdd(&sCnt[a], scale * pAct[a]);   // LDS float atomics
    }
  }
  __syncthreads();

  if (t < An) {
    float m = -INFINITY;
    float c[An];
#pragma unroll
    for (int i = 0; i < An; ++i) { c[i] = sCnt[i]; m = fmaxf(m, c[i]); }
    float s = 0.f;
#pragma unroll
    for (int i = 0; i < An; ++i) s += expf(c[i] - m);
    out[t] = expf(c[t] - m) / s;
  }
}

extern "C" void kernel_launch(void* const* d_in, const int* in_sizes, int n_in,
                              void* d_out, int out_size, void* d_ws, size_t ws_size,
                              hipStream_t stream) {
  const float* obs    = (const float*)d_in[0];
  const float* conv_w = (const float*)d_in[1];
  const float* conv_b = (const float*)d_in[2];
  const float* w_obj  = (const float*)d_in[3];
  const float* w_pos  = (const float*)d_in[4];
  const float* w_neg  = (const float*)d_in[5];
  const float* w_act  = (const float*)d_in[6];
  const float* w_dir  = (const float*)d_in[7];
  const float* w_not  = (const float*)d_in[8];
  float* out = (float*)d_out;

  uint8_t* ws = (uint8_t*)d_ws;
  int*     bf    = (int*)(ws + 0);        // 64*16*4 = 4096
  uint8_t* grid8 = ws + 4096;             // 16384

  k_prep<<<dim3(PBLK), dim3(256), 0, stream>>>(obs, conv_w, conv_b, grid8, bf);
  k_final<<<dim3(1), dim3(1024), 0, stream>>>(grid8, bf,
                                              w_obj, w_pos, w_neg, w_act, w_dir, w_not,
                                              out);
}

// Round 10
// 107.826 us; speedup vs baseline: 1.2157x; 1.2157x over previous
//
#include <hip/hip_runtime.h>
#include <stdint.h>
#include <math.h>

#define Hh 128
#define Ww 128
#define Vn 16
#define An 8
#define Pn 64
#define Cn 3
#define HWc (Hh*Ww)
#define MAXT 50

// DIRS = [(1,0),(0,1),(-1,0),(0,-1),(1,1),(-1,1),(1,-1),(-1,-1)]  (dr, dc)
__constant__ int c_DR[8] = {1, 0, -1, 0, 1, -1, 1, -1};
__constant__ int c_DC[8] = {0, 1, 0, -1, 1, 1, -1, -1};

// ---- prep: conv3x3(zero-pad)+argmax over 16 ch; per-block first-occurrence
//      reduced in LDS then plain stores to bf[block][16]. enc = HWc - cell.
__global__ __launch_bounds__(1024) void k_prep(const float* __restrict__ obs,
                                               const float* __restrict__ cw,
                                               const float* __restrict__ cb,
                                               uint8_t* __restrict__ grid8,
                                               int* __restrict__ bf) {
  __shared__ float sw[Vn * Cn * 9];
  __shared__ float sb[Vn];
  __shared__ int lf[Vn];
  int t = threadIdx.x;
  for (int i = t; i < Vn * Cn * 9; i += 1024) sw[i] = cw[i];
  if (t < Vn) { sb[t] = cb[t]; lf[t] = 0; }
  __syncthreads();

  int cell = blockIdx.x * 1024 + t;
  int r = cell >> 7, c = cell & 127;
  float o[27];
#pragma unroll
  for (int ch = 0; ch < Cn; ++ch)
#pragma unroll
    for (int ky = 0; ky < 3; ++ky)
#pragma unroll
      for (int kx = 0; kx < 3; ++kx) {
        int rr = r + ky - 1, cc = c + kx - 1;
        o[ch * 9 + ky * 3 + kx] =
            ((unsigned)rr < (unsigned)Hh && (unsigned)cc < (unsigned)Ww)
                ? obs[(ch * Hh + rr) * Ww + cc] : 0.f;
      }
  float best = -INFINITY; int bi = 0;
#pragma unroll
  for (int v = 0; v < Vn; ++v) {
    float acc = sb[v];
#pragma unroll
    for (int i = 0; i < 27; ++i) acc += o[i] * sw[v * 27 + i];
    if (acc > best) { best = acc; bi = v; }  // first max on tie
  }
  grid8[cell] = (uint8_t)bi;
  atomicMax(&lf[bi], HWc - cell);
  __syncthreads();
  if (t < Vn) bf[blockIdx.x * Vn + t] = lf[t];
}

__device__ __forceinline__ void softmaxS(const float* __restrict__ w,
                                         float* __restrict__ o, int n, int os) {
  float m = -INFINITY;
  for (int i = 0; i < n; ++i) m = fmaxf(m, w[i]);
  float s = 0.f;
  for (int i = 0; i < n; ++i) { float e = expf(w[i] - m); o[i * os] = e; s += e; }
  float inv = 1.f / s;
  for (int i = 0; i < n; ++i) o[i * os] *= inv;
}

// ---- everything else, ONE block of 1024 (16 waves). Sorted-suffix-sum
// replaces the 16x16 (pos,neg) bit double-sum:
//   inner(od) = sum_{pos finite} Ppos[pos] * G(F[pos]),
//   G(f) = sum_{F[neg] >= f} Pneg[neg]
// computed by one descending-F 16-step walk (acc += Pneg; inner += fin*Ppos*acc).
// Exact: finite F are distinct (one cell per step); ties only at F=64 where the
// pos side is gated. q_p = sum_od PObj[o]*PDir[d]*inner; counts as in R7/R8.
__global__ __launch_bounds__(1024) void k_final(const uint8_t* __restrict__ grid8g,
                                                const int* __restrict__ bf,
                                                const float* __restrict__ w_obj,
                                                const float* __restrict__ w_pos,
                                                const float* __restrict__ w_neg,
                                                const float* __restrict__ w_act,
                                                const float* __restrict__ w_dir,
                                                const float* __restrict__ w_not,
                                                float* __restrict__ out) {
  __shared__ uint8_t g8[HWc];          // 16 KB
  __shared__ float2 sPPN[16 * 64];     // (pos,neg) pairs, [v][p], 8 KB
  __shared__ float PObjT[16 * 64];     // [o][p], 4 KB
  __shared__ float PDirT[8 * 64];      // [d][p], 2 KB
  __shared__ float sAct[64 * 8];       // [p][a], 2 KB
  __shared__ float sNot[64 * 2];       // [p][2]
  __shared__ uint8_t Ftab[128 * 16];   // F per (od, v), 2 KB
  __shared__ uint32_t idxLo[128], idxHi[128], finM[128];
  __shared__ float qPart[16 * 64];     // 4 KB
  __shared__ int lf16[Vn], sEx[Vn], sFr[Vn], sFc[Vn];
  __shared__ float sCnt[An];

  int t = threadIdx.x;
  int wave = t >> 6, lane = t & 63;

  if (t < Vn) lf16[t] = 0;
  if (t < An) sCnt[t] = 0.f;
  __syncthreads();

  // stage grid (one uint4 per thread) + bf reduce + pi tables
  ((uint4*)g8)[t] = ((const uint4*)grid8g)[t];
  if (t < 256) atomicMax(&lf16[t & 15], bf[t]);
  {
    int p = lane;
    if      (wave == 0) softmaxS(w_obj + p * 16, &PObjT[p], 16, 64);
    else if (wave == 1) softmaxS(w_pos + p * 16, &((float*)sPPN)[p * 2],     16, 128);
    else if (wave == 2) softmaxS(w_neg + p * 16, &((float*)sPPN)[p * 2 + 1], 16, 128);
    else if (wave == 3) softmaxS(w_act + p * 8,  &sAct[p * 8], 8, 1);
    else if (wave == 4) softmaxS(w_dir + p * 8,  &PDirT[p], 8, 64);
    else if (wave == 5) softmaxS(w_not + p * 2,  &sNot[p * 2], 2, 1);
  }
  __syncthreads();

  if (t < Vn) {
    int m = lf16[t];
    int ex = (m >= 1);
    sEx[t] = ex;
    int cell = ex ? (HWc - m) : 0;
    sFr[t] = cell >> 7;
    sFc[t] = cell & 127;
  }
  __syncthreads();

  // F table: 128 (so,sd) combos, 8 per wave; lane = ray step-1; 16 ballots
#pragma unroll
  for (int j = 0; j < 8; ++j) {
    int od = wave * 8 + j;
    int so = od >> 3, sd = od & 7;
    int step = lane + 1;
    int val = 255;
    if (step <= MAXT && sEx[so]) {
      int r = sFr[so] + step * c_DR[sd];
      int c = sFc[so] + step * c_DC[sd];
      if ((unsigned)r < (unsigned)Hh && (unsigned)c < (unsigned)Ww)
        val = g8[(r << 7) + c];
    }
#pragma unroll
    for (int v = 0; v < Vn; ++v) {
      unsigned long long m = __ballot(val == v);
      if (lane == v) Ftab[od * 16 + v] = m ? (uint8_t)__builtin_ctzll(m) : (uint8_t)64;
    }
  }
  __syncthreads();

  // per-od descending-F rank (unique: strictly-greater count + earlier-index ties)
  if (t < 128) {
    int F[16];
#pragma unroll
    for (int k = 0; k < 4; ++k) {
      uint32_t w = ((const uint32_t*)Ftab)[t * 4 + k];
#pragma unroll
      for (int b = 0; b < 4; ++b) F[k * 4 + b] = (w >> (8 * b)) & 0xFF;
    }
    uint32_t lo = 0, hi = 0, fm = 0;
#pragma unroll
    for (int v = 0; v < 16; ++v) {
      int rk = 0;
#pragma unroll
      for (int n = 0; n < 16; ++n)
        if (n != v) rk += (F[n] > F[v]) || (F[n] == F[v] && n < v);
      if (rk < 8) lo |= (uint32_t)v << (4 * rk);
      else        hi |= (uint32_t)v << (4 * (rk - 8));
      fm |= (F[v] < 64 ? 1u : 0u) << rk;
    }
    idxLo[t] = lo; idxHi[t] = hi; finM[t] = fm;
  }
  __syncthreads();

  // q_p: lane = p, wave handles 8 od; suffix-sum walk per od
  {
    float qAcc = 0.f;
#pragma unroll
    for (int j = 0; j < 8; ++j) {
      int od = wave * 8 + j;
      uint32_t lo = idxLo[od], hi = idxHi[od], fm = finM[od];
      float acc = 0.f, inner = 0.f;
#pragma unroll
      for (int r = 0; r < 16; ++r) {
        uint32_t i = ((r < 8) ? (lo >> (4 * r)) : (hi >> (4 * (r - 8)))) & 15u;
        float2 pn = sPPN[i * 64 + lane];
        acc += pn.y;
        inner = fmaf(((fm >> r) & 1u) ? pn.x : 0.f, acc, inner);
      }
      int o = od >> 3, d = od & 7;
      qAcc = fmaf(PObjT[o * 64 + lane] * PDirT[d * 64 + lane], inner, qAcc);
    }
    qPart[wave * 64 + lane] = qAcc;
  }
  __syncthreads();

  if (t < 64) {
    float q = 0.f;
#pragma unroll
    for (int w = 0; w < 16; ++w) q += qPart[w * 64 + t];
    float r = q * sNot[t * 2] + (1.f - q) * sNot[t * 2 + 1];
    float scale = 16384.f * r;
#pragma unroll
    for (int a = 0; a < 8; ++a)
      atomicAdd(&sCnt[a], scale * sAct[t * 8 + a]);
  }
  __syncthreads();

  if (t < An) {
    float m = -INFINITY;
    float c[An];
#pragma unroll
    for (int i = 0; i < An; ++i) { c[i] = sCnt[i]; m = fmaxf(m, c[i]); }
    float s = 0.f;
#pragma unroll
    for (int i = 0; i < An; ++i) s += expf(c[i] - m);
    out[t] = expf(c[t] - m) / s;
  }
}

extern "C" void kernel_launch(void* const* d_in, const int* in_sizes, int n_in,
                              void* d_out, int out_size, void* d_ws, size_t ws_size,
                              hipStream_t stream) {
  const float* obs    = (const float*)d_in[0];
  const float* conv_w = (const float*)d_in[1];
  const float* conv_b = (const float*)d_in[2];
  const float* w_obj  = (const float*)d_in[3];
  const float* w_pos  = (const float*)d_in[4];
  const float* w_neg  = (const float*)d_in[5];
  const float* w_act  = (const float*)d_in[6];
  const float* w_dir  = (const float*)d_in[7];
  const float* w_not  = (const float*)d_in[8];
  float* out = (float*)d_out;

  uint8_t* ws = (uint8_t*)d_ws;
  int*     bf    = (int*)(ws + 0);        // 16 blocks * 16 * 4 = 1024 B
  uint8_t* grid8 = ws + 1024;             // 16384 B

  k_prep<<<dim3(16), dim3(1024), 0, stream>>>(obs, conv_w, conv_b, grid8, bf);
  k_final<<<dim3(1), dim3(1024), 0, stream>>>(grid8, bf,
                                              w_obj, w_pos, w_neg, w_act, w_dir, w_not,
                                              out);
}